// Round 12
// baseline (45.289 us; speedup 1.0000x reference)
//
#include <hip/hip_runtime.h>

// QRNN fused kernel for MI355X.
// B=64, S=2048, VOCAB=128, HIDDEN=256, gates=768, emb=124, num=7.
//
//  - precompute_kernel (one grid, three roles):
//      blocks 0..255  : GEMM, one channel j per block. Writes fp16-packed exp2-domain
//                       table G2h[e][j]={z',f'} + f32 Go[e][j]=o'.
//      block  256     : rank-4 numeric weights Wg4/Wgo4.
//      blocks 257..384: rank-4 records XpA[b*S+t]={eo=e<<8, y0,y1,y2}, XpB=y3.
//  - scan_kernel: affine recurrence h = f*h + (1-f)*z, chunked scan, CHUNKS=64 x 32.
//      KEY CHANGE (r9 counters showed scan VGPR_Count=16 -> compiler built ZERO
//      software pipeline; every step is load->wait(0)->use): each thread now runs
//      TWO INDEPENDENT (b,c)-chunk streams (separate records, separate A/Bv chains,
//      SAME channel j so weights shared). Independent dataflow forces 2 loads in
//      flight -- the compiler cannot serialize it away. CHUNKS=64 doubles TLP.
//      Table = 32KB fp16 j-quarter in LDS (4 blocks/CU -> 32 waves/CU), records =
//      wave-uniform broadcast VMEM loads, launch_bounds(512,4) for VGPR headroom.
//  - combine_kernel: fold 64 chunk affines, apply o (last step), dot W_out.

typedef float    f32x2 __attribute__((ext_vector_type(2)));
typedef float    f32x4 __attribute__((ext_vector_type(4)));
typedef _Float16 f16x2 __attribute__((ext_vector_type(2)));

#define NB 64
#define NS 2048
#define NH 256
#define CHUNKS 64
#define STEPS (NS / CHUNKS)   // 32
#define LOG2E 1.4426950408889634f
#define PAD 129
#define JH 64                 // channels per j-quarter

__global__ __launch_bounds__(256) void precompute_kernel(
    const float* __restrict__ X,     // [B][S][8]
    const float* __restrict__ emb,   // [128][124]
    const float* __restrict__ Wn,    // [4][7]
    const float* __restrict__ bn,    // [4]
    const float* __restrict__ Wc,    // [768][128]
    const float* __restrict__ bc,    // [768]
    f16x2* __restrict__ G2h,         // out [128e][256j]  (z', f') fp16, exp2-domain
    float* __restrict__ Go,          // out [128e][256j]  o' (f32)
    f32x2* __restrict__ Wg4,         // out [4][256]
    float* __restrict__ Wgo4,        // out [4][256]
    f32x4* __restrict__ XpA,         // out [B*S] {eo, y0, y1, y2}
    float* __restrict__ XpB)         // out [B*S] y3
{
    const int tid = threadIdx.x;
    const int blk = blockIdx.x;

    if (blk < 256) {
        __shared__ float M[124 * PAD];      // emb^T: M[k*PAD + e] = emb[e][k]
        __shared__ float P[3][2][128];      // k-half partial sums
        {
            const int e = tid >> 1, half = tid & 1;
            const f32x4* er4 = (const f32x4*)(emb + (size_t)e * 124);
            #pragma unroll
            for (int i = 0; i < 16; ++i) {
                const int idx = half * 16 + i;
                if (idx < 31) {
                    const f32x4 v = er4[idx];
                    const int k0 = idx * 4;
                    M[(k0 + 0) * PAD + e] = v.x;
                    M[(k0 + 1) * PAD + e] = v.y;
                    M[(k0 + 2) * PAD + e] = v.z;
                    M[(k0 + 3) * PAD + e] = v.w;
                }
            }
        }
        __syncthreads();

        const int e = tid & 127;
        const int h = tid >> 7;          // k-half
        const int j = blk;               // channel
        const int k0 = h * 62;

        const float* __restrict__ wzr = Wc + (size_t)j * 128;
        const float* __restrict__ wfr = Wc + (size_t)(j + 256) * 128;
        const float* __restrict__ wor = Wc + (size_t)(j + 512) * 128;

        float az = 0.f, af = 0.f, ao = 0.f;
        #pragma unroll 31
        for (int i = 0; i < 62; ++i) {
            const int k = k0 + i;
            const float mv = M[k * PAD + e];
            az = fmaf(wzr[k], mv, az);
            af = fmaf(wfr[k], mv, af);
            ao = fmaf(wor[k], mv, ao);
        }
        P[0][h][e] = az; P[1][h][e] = af; P[2][h][e] = ao;
        __syncthreads();

        if (h == 0) {
            float sz = P[0][0][e] + P[0][1][e] + bc[j];
            float sf = P[1][0][e] + P[1][1][e] + bc[j + 256];
            float so = P[2][0][e] + P[2][1][e] + bc[j + 512];
            #pragma unroll
            for (int m = 0; m < 4; ++m) {
                const float bm = bn[m];
                sz = fmaf(wzr[124 + m], bm, sz);
                sf = fmaf(wfr[124 + m], bm, sf);
                so = fmaf(wor[124 + m], bm, so);
            }
            G2h[(size_t)e * NH + j] = (f16x2){(_Float16)(sz * (-2.0f * LOG2E)),
                                              (_Float16)(sf * (-LOG2E))};
            Go[(size_t)e * NH + j] = so * (-LOG2E);
        }
    } else if (blk == 256) {
        const int j = tid;
        #pragma unroll
        for (int m = 0; m < 4; ++m) {
            const float wz = Wc[(size_t)j * 128 + 124 + m];
            const float wf = Wc[(size_t)(j + 256) * 128 + 124 + m];
            const float wo = Wc[(size_t)(j + 512) * 128 + 124 + m];
            Wg4[m * NH + j]  = (f32x2){wz * (-2.0f * LOG2E), wf * (-LOG2E)};
            Wgo4[m * NH + j] = wo * (-LOG2E);
        }
    } else {
        // rank-4 record extraction: 128 blocks x 1024 records
        const f32x4* X4 = (const f32x4*)X;
        float wn[4][7];
        #pragma unroll
        for (int m = 0; m < 4; ++m)
            #pragma unroll
            for (int n = 0; n < 7; ++n) wn[m][n] = Wn[m * 7 + n];

        const int base = (blk - 257) * 1024 + tid;
        #pragma unroll
        for (int u = 0; u < 4; ++u) {
            const int idx = base + u * 256;
            const f32x4 xa = X4[(size_t)idx * 2];
            const f32x4 xb = X4[(size_t)idx * 2 + 1];
            const int eo = ((int)xa.x) << 8;    // byte offset of 256B LDS quarter-row
            const float xs[7] = {xa.y, xa.z, xa.w, xb.x, xb.y, xb.z, xb.w};
            float y[4];
            #pragma unroll
            for (int m = 0; m < 4; ++m) {
                float s = 0.0f;
                #pragma unroll
                for (int n = 0; n < 7; ++n) s = fmaf(wn[m][n], xs[n], s);
                y[m] = s;
            }
            XpA[idx] = (f32x4){__int_as_float(eo), y[0], y[1], y[2]};
            XpB[idx] = y[3];
        }
    }
}

__global__ __launch_bounds__(512, 4) void scan_kernel(
    const f32x4* __restrict__ XpA,   // [B*S] {eo, y0, y1, y2}
    const float* __restrict__ XpB,   // [B*S] y3
    const f16x2* __restrict__ G2h,   // [128][256] fp16 (z',f')
    const float* __restrict__ Go,    // [128][256]
    const f32x2* __restrict__ Wg4,   // [4][256]
    const float* __restrict__ Wgo4,  // [4][256]
    float* __restrict__ AB,          // [CHUNKS][B][2][256]
    float* __restrict__ Olast)       // [B][256]
{
    __shared__ f16x2 T[128 * JH];    // 32 KB: this block's j-quarter of the table

    const int tid = threadIdx.x;
    const int jq = blockIdx.y;
    const int jbase = jq * JH;

    // ---- stage j-quarter of G2h: 2048 uint4, coalesced, 4 iters
    {
        const uint4* __restrict__ src = (const uint4*)G2h;   // row e = 64 uint4
        uint4* dst = (uint4*)T;
        const int colbase = jq * 16;                          // 16 uint4 per quarter-row
        #pragma unroll
        for (int i = tid; i < 2048; i += 512) {
            const int e = i >> 4, c16 = i & 15;
            dst[i] = src[e * 64 + colbase + c16];
        }
    }
    __syncthreads();

    const int jj = tid & (JH - 1);       // 0..63  (wave = one row: record addrs wave-uniform)
    const int row = tid >> 6;            // 0..7
    const int j = jbase + jj;
    const int widx0 = (int)blockIdx.x * 16 + row;   // stream 0
    const int widx1 = widx0 + 8;                    // stream 1 (same b, c+8)
    const int b  = widx0 >> 6;
    const int c0 = widx0 & (CHUNKS - 1);
    const int c1 = widx1 & (CHUNKS - 1);

    const f32x4* __restrict__ xa0 = XpA + ((size_t)b * NS + (size_t)c0 * STEPS);
    const float* __restrict__ xb0 = XpB + ((size_t)b * NS + (size_t)c0 * STEPS);
    const f32x4* __restrict__ xa1 = XpA + ((size_t)b * NS + (size_t)c1 * STEPS);
    const float* __restrict__ xb1 = XpB + ((size_t)b * NS + (size_t)c1 * STEPS);
    const char*  __restrict__ Tb = (const char*)T;
    const int jj4 = jj * 4;

    const f32x2 w0 = Wg4[0 * NH + j];
    const f32x2 w1 = Wg4[1 * NH + j];
    const f32x2 w2 = Wg4[2 * NH + j];
    const f32x2 w3 = Wg4[3 * NH + j];

    float A0 = 1.0f, B0 = 0.0f, A1 = 1.0f, B1 = 0.0f;
    #pragma unroll
    for (int t = 0; t < STEPS; ++t) {
        // two independent streams: compiler must keep both load bundles in flight
        const f32x4 ra0 = xa0[t];
        const float ry0 = xb0[t];
        const f32x4 ra1 = xa1[t];
        const float ry1 = xb1[t];
        const unsigned eo0 = (unsigned)__float_as_int(ra0.x);   // e<<8
        const unsigned eo1 = (unsigned)__float_as_int(ra1.x);
        const f16x2 gh0 = *(const f16x2*)(Tb + eo0 + jj4);      // ds_read_b32
        const f16x2 gh1 = *(const f16x2*)(Tb + eo1 + jj4);

        f32x2 g0 = (f32x2){(float)gh0.x, (float)gh0.y};
        g0 = __builtin_elementwise_fma(w0, (f32x2){ra0.y, ra0.y}, g0);
        g0 = __builtin_elementwise_fma(w1, (f32x2){ra0.z, ra0.z}, g0);
        g0 = __builtin_elementwise_fma(w2, (f32x2){ra0.w, ra0.w}, g0);
        g0 = __builtin_elementwise_fma(w3, (f32x2){ry0, ry0}, g0);

        f32x2 g1 = (f32x2){(float)gh1.x, (float)gh1.y};
        g1 = __builtin_elementwise_fma(w0, (f32x2){ra1.y, ra1.y}, g1);
        g1 = __builtin_elementwise_fma(w1, (f32x2){ra1.z, ra1.z}, g1);
        g1 = __builtin_elementwise_fma(w2, (f32x2){ra1.w, ra1.w}, g1);
        g1 = __builtin_elementwise_fma(w3, (f32x2){ry1, ry1}, g1);

        const float ez0 = __builtin_amdgcn_exp2f(g0.x);
        const float ef0 = __builtin_amdgcn_exp2f(g0.y);
        const float ez1 = __builtin_amdgcn_exp2f(g1.x);
        const float ef1 = __builtin_amdgcn_exp2f(g1.y);
        const float az0 = 1.0f + ez0, af0 = 1.0f + ef0;
        const float az1 = 1.0f + ez1, af1 = 1.0f + ef1;
        const float r0 = __builtin_amdgcn_rcpf(az0 * af0);
        const float r1 = __builtin_amdgcn_rcpf(az1 * af1);
        const float f0 = r0 * az0;
        const float f1 = r1 * az1;
        const float z0 = fmaf(2.0f, r0 * af0, -1.0f);
        const float z1 = fmaf(2.0f, r1 * af1, -1.0f);

        A0 *= f0; B0 = fmaf(f0, B0 - z0, z0);
        A1 *= f1; B1 = fmaf(f1, B1 - z1, z1);
    }

    AB[(((size_t)c0 * NB + b) * 2 + 0) * NH + j] = A0;
    AB[(((size_t)c0 * NB + b) * 2 + 1) * NH + j] = B0;
    AB[(((size_t)c1 * NB + b) * 2 + 0) * NH + j] = A1;
    AB[(((size_t)c1 * NB + b) * 2 + 1) * NH + j] = B1;

    if (c1 == CHUNKS - 1) {
        const f32x4 la = xa1[STEPS - 1];
        const float ly3 = xb1[STEPS - 1];
        const size_t eo = (size_t)(unsigned)__float_as_int(la.x);  // e<<8
        float go = *(const float*)((const char*)Go + (eo << 2) + (size_t)j * 4);
        go = fmaf(Wgo4[0 * NH + j], la.y, go);
        go = fmaf(Wgo4[1 * NH + j], la.z, go);
        go = fmaf(Wgo4[2 * NH + j], la.w, go);
        go = fmaf(Wgo4[3 * NH + j], ly3, go);
        Olast[b * NH + j] = __builtin_amdgcn_rcpf(1.0f + __builtin_amdgcn_exp2f(go));
    }
}

__global__ __launch_bounds__(256) void combine_kernel(
    const float* __restrict__ AB,     // [CHUNKS][B][2][256]
    const float* __restrict__ Olast,  // [B][256]
    const float* __restrict__ Wout,   // [1][256]
    const float* __restrict__ bout,   // [1]
    float* __restrict__ out)          // [B][1]
{
    const int b = blockIdx.x;
    const int j = threadIdx.x;

    float h = 0.0f;
    #pragma unroll 8
    for (int c = 0; c < CHUNKS; ++c) {
        const float A  = AB[(((size_t)c * NB + b) * 2 + 0) * NH + j];
        const float Bv = AB[(((size_t)c * NB + b) * 2 + 1) * NH + j];
        h = fmaf(A, h, Bv);
    }
    float v = Olast[b * NH + j] * h * Wout[j];

    #pragma unroll
    for (int off = 32; off > 0; off >>= 1) v += __shfl_down(v, off);
    __shared__ float red[4];
    if ((j & 63) == 0) red[j >> 6] = v;
    __syncthreads();
    if (j == 0) out[b] = red[0] + red[1] + red[2] + red[3] + bout[0];
}

extern "C" void kernel_launch(void* const* d_in, const int* in_sizes, int n_in,
                              void* d_out, int out_size, void* d_ws, size_t ws_size,
                              hipStream_t stream) {
    const float* X    = (const float*)d_in[0];
    const float* emb  = (const float*)d_in[1];
    const float* Wn   = (const float*)d_in[2];
    const float* bn   = (const float*)d_in[3];
    const float* Wc   = (const float*)d_in[4];
    const float* bc   = (const float*)d_in[5];
    const float* Wout = (const float*)d_in[6];
    const float* bout = (const float*)d_in[7];
    float* out = (float*)d_out;

    char* w = (char*)d_ws;
    f16x2* G2h  = (f16x2*)w;   w += 128 * NH * sizeof(f16x2);   // 128 KB
    float* Go   = (float*)w;   w += 128 * NH * sizeof(float);   // 128 KB
    f32x2* Wg4  = (f32x2*)w;   w += 4 * NH * sizeof(f32x2);
    float* Wgo4 = (float*)w;   w += 4 * NH * sizeof(float);
    float* AB   = (float*)w;   w += (size_t)CHUNKS * NB * 2 * NH * sizeof(float); // 8 MB
    float* Ol   = (float*)w;   w += NB * NH * sizeof(float);
    f32x4* XpA  = (f32x4*)w;   w += (size_t)NB * NS * sizeof(f32x4);              // 2 MB
    float* XpB  = (float*)w;   w += (size_t)NB * NS * sizeof(float);              // 512 KB

    precompute_kernel<<<385, 256, 0, stream>>>(X, emb, Wn, bn, Wc, bc,
                                               G2h, Go, Wg4, Wgo4, XpA, XpB);
    dim3 gridS(256, 4);
    scan_kernel<<<gridS, 512, 0, stream>>>(XpA, XpB, G2h, Go, Wg4, Wgo4, AB, Ol);
    combine_kernel<<<NB, 256, 0, stream>>>(AB, Ol, Wout, bout, out);
}

// Round 13
// 41.971 us; speedup vs baseline: 1.0791x; 1.0791x over previous
//
#include <hip/hip_runtime.h>

// QRNN fused kernel for MI355X.
// B=64, S=2048, VOCAB=128, HIDDEN=256, gates=768, emb=124, num=7.
//
//  - precompute_kernel (one grid, three roles):
//      blocks 0..255  : GEMM, one channel j per block. Writes fp16-packed exp2-domain
//                       table G2h[e][j]={z',f'} + f32 Go[e][j]=o'.
//      block  256     : rank-4 numeric weights Wg4/Wgo4.
//      blocks 257..384: 16-BYTE rank-4 records Xp[b*S+t] = {eo=e<<9 bits, y0 f32,
//                       y1 f32, (y2,y3) f16x2} -> scan does ONE broadcast VMEM load
//                       per step (was dwordx4+dword).
//  - scan_kernel: affine recurrence h = f*h + (1-f)*z, chunked scan (32 x 64 steps).
//      MODEL (r4-r12 all pinned at ~29-31us): wall = STEPS x per-step serial chain
//      (record load -> eo -> table load -> gate math -> update, ~500cy). TLP spreads
//      waves across SIMDs but cannot shorten one wave's serial chain; r9 showed
//      VGPR_Count=16, i.e. the compiler pipelines NOTHING. Fix: static prefetch
//      rings with clean counters -- records (VMEM broadcast, vmcnt, depth-4 ring
//      issued 3 ahead) and table (LDS, lgkmcnt DS-only in-order, depth-2 ring
//      issued 1 ahead). All ring indices static under #pragma unroll 4. eo masked
//      to 64KB so tail-overrun prefetches are safe (+4 pad records). Residual
//      per-step chain = scan update + issue (~60-100cy) -> ~4x shorter wall.
//  - combine_kernel: fold 32 chunk affines, apply o (last step), dot W_out.

typedef float    f32x2 __attribute__((ext_vector_type(2)));
typedef float    f32x4 __attribute__((ext_vector_type(4)));
typedef _Float16 f16x2 __attribute__((ext_vector_type(2)));

#define NB 64
#define NS 2048
#define NH 256
#define CHUNKS 32
#define STEPS (NS / CHUNKS)   // 64
#define LOG2E 1.4426950408889634f
#define PAD 129
#define JH 128                // channels per j-half

union f16x2_f32 { f16x2 h; float f; };

__global__ __launch_bounds__(256) void precompute_kernel(
    const float* __restrict__ X,     // [B][S][8]
    const float* __restrict__ emb,   // [128][124]
    const float* __restrict__ Wn,    // [4][7]
    const float* __restrict__ bn,    // [4]
    const float* __restrict__ Wc,    // [768][128]
    const float* __restrict__ bc,    // [768]
    f16x2* __restrict__ G2h,         // out [128e][256j]  (z', f') fp16, exp2-domain
    float* __restrict__ Go,          // out [128e][256j]  o' (f32)
    f32x2* __restrict__ Wg4,         // out [4][256]
    float* __restrict__ Wgo4,        // out [4][256]
    f32x4* __restrict__ Xp)          // out [B*S+4] {eo, y0, y1, y2y3}
{
    const int tid = threadIdx.x;
    const int blk = blockIdx.x;

    if (blk < 256) {
        __shared__ float M[124 * PAD];      // emb^T: M[k*PAD + e] = emb[e][k]
        __shared__ float P[3][2][128];      // k-half partial sums
        {
            const int e = tid >> 1, half = tid & 1;
            const f32x4* er4 = (const f32x4*)(emb + (size_t)e * 124);
            #pragma unroll
            for (int i = 0; i < 16; ++i) {
                const int idx = half * 16 + i;
                if (idx < 31) {
                    const f32x4 v = er4[idx];
                    const int k0 = idx * 4;
                    M[(k0 + 0) * PAD + e] = v.x;
                    M[(k0 + 1) * PAD + e] = v.y;
                    M[(k0 + 2) * PAD + e] = v.z;
                    M[(k0 + 3) * PAD + e] = v.w;
                }
            }
        }
        __syncthreads();

        const int e = tid & 127;
        const int h = tid >> 7;          // k-half
        const int j = blk;               // channel
        const int k0 = h * 62;

        const float* __restrict__ wzr = Wc + (size_t)j * 128;
        const float* __restrict__ wfr = Wc + (size_t)(j + 256) * 128;
        const float* __restrict__ wor = Wc + (size_t)(j + 512) * 128;

        float az = 0.f, af = 0.f, ao = 0.f;
        #pragma unroll 31
        for (int i = 0; i < 62; ++i) {
            const int k = k0 + i;
            const float mv = M[k * PAD + e];
            az = fmaf(wzr[k], mv, az);
            af = fmaf(wfr[k], mv, af);
            ao = fmaf(wor[k], mv, ao);
        }
        P[0][h][e] = az; P[1][h][e] = af; P[2][h][e] = ao;
        __syncthreads();

        if (h == 0) {
            float sz = P[0][0][e] + P[0][1][e] + bc[j];
            float sf = P[1][0][e] + P[1][1][e] + bc[j + 256];
            float so = P[2][0][e] + P[2][1][e] + bc[j + 512];
            #pragma unroll
            for (int m = 0; m < 4; ++m) {
                const float bm = bn[m];
                sz = fmaf(wzr[124 + m], bm, sz);
                sf = fmaf(wfr[124 + m], bm, sf);
                so = fmaf(wor[124 + m], bm, so);
            }
            G2h[(size_t)e * NH + j] = (f16x2){(_Float16)(sz * (-2.0f * LOG2E)),
                                              (_Float16)(sf * (-LOG2E))};
            Go[(size_t)e * NH + j] = so * (-LOG2E);
        }
    } else if (blk == 256) {
        const int j = tid;
        #pragma unroll
        for (int m = 0; m < 4; ++m) {
            const float wz = Wc[(size_t)j * 128 + 124 + m];
            const float wf = Wc[(size_t)(j + 256) * 128 + 124 + m];
            const float wo = Wc[(size_t)(j + 512) * 128 + 124 + m];
            Wg4[m * NH + j]  = (f32x2){wz * (-2.0f * LOG2E), wf * (-LOG2E)};
            Wgo4[m * NH + j] = wo * (-LOG2E);
        }
    } else {
        // 16B rank-4 record extraction: 128 blocks x 1024 records
        const f32x4* X4 = (const f32x4*)X;
        float wn[4][7];
        #pragma unroll
        for (int m = 0; m < 4; ++m)
            #pragma unroll
            for (int n = 0; n < 7; ++n) wn[m][n] = Wn[m * 7 + n];

        const int base = (blk - 257) * 1024 + tid;
        #pragma unroll
        for (int u = 0; u < 4; ++u) {
            const int idx = base + u * 256;
            const f32x4 xa = X4[(size_t)idx * 2];
            const f32x4 xb = X4[(size_t)idx * 2 + 1];
            const int eo = ((int)xa.x) << 9;    // byte offset of 512B LDS table row
            const float xs[7] = {xa.y, xa.z, xa.w, xb.x, xb.y, xb.z, xb.w};
            float y[4];
            #pragma unroll
            for (int m = 0; m < 4; ++m) {
                float s = 0.0f;
                #pragma unroll
                for (int n = 0; n < 7; ++n) s = fmaf(wn[m][n], xs[n], s);
                y[m] = s;
            }
            union f16x2_f32 u23;
            u23.h = (f16x2){(_Float16)y[2], (_Float16)y[3]};
            Xp[idx] = (f32x4){__int_as_float(eo), y[0], y[1], u23.f};
        }
    }
}

__global__ __launch_bounds__(1024) void scan_kernel(
    const f32x4* __restrict__ Xp,    // [B*S+4] {eo, y0, y1, y2y3}
    const f16x2* __restrict__ G2h,   // [128][256] fp16 (z',f')
    const float* __restrict__ Go,    // [128][256]
    const f32x2* __restrict__ Wg4,   // [4][256]
    const float* __restrict__ Wgo4,  // [4][256]
    float* __restrict__ AB,          // [CHUNKS][B][2][256]
    float* __restrict__ Olast)       // [B][256]
{
    __shared__ f16x2 T[128 * JH];    // 64 KB: this block's j-half of the table

    const int tid = threadIdx.x;
    const int jbase = blockIdx.y * JH;

    // ---- stage j-half of G2h: 4096 uint4, coalesced, 4 iters
    {
        const uint4* __restrict__ src = (const uint4*)G2h;   // row e = 64 uint4
        uint4* dst = (uint4*)T;
        const int colbase = jbase >> 2;                       // 32 uint4 per half-row
        #pragma unroll
        for (int i = tid; i < 4096; i += 1024) {
            const int e = i >> 5, c16 = i & 31;
            dst[i] = src[e * 64 + colbase + c16];
        }
    }
    __syncthreads();

    const int slice = tid >> 7;          // 0..7 (wave-uniform: wave sits in one slice)
    const int jj = tid & (JH - 1);       // 0..127
    const int widx = (int)blockIdx.x * 8 + slice;
    const int b = widx >> 5;
    const int c = widx & (CHUNKS - 1);
    const int j = jbase + jj;

    const f32x4* __restrict__ xa = Xp + ((size_t)b * NS + (size_t)c * STEPS);
    const char*  __restrict__ Tb = (const char*)T;
    const int jj4 = jj * 4;

    const f32x2 w0 = Wg4[0 * NH + j];
    const f32x2 w1 = Wg4[1 * NH + j];
    const f32x2 w2 = Wg4[2 * NH + j];
    const f32x2 w3 = Wg4[3 * NH + j];

    // ---- static prefetch rings: records depth 4 (3 ahead), table depth 2 (1 ahead)
    f32x4 rec[4];
    f16x2 tv[2];
    rec[0] = xa[0];
    rec[1] = xa[1];
    rec[2] = xa[2];
    {
        const unsigned eo0 = (unsigned)__float_as_int(rec[0].x) & 0xFE00u;
        tv[0] = *(const f16x2*)(Tb + eo0 + jj4);
    }

    float A = 1.0f, Bv = 0.0f;
    #pragma unroll 4
    for (int t = 0; t < STEPS; ++t) {
        rec[(t + 3) & 3] = xa[t + 3];                         // vmcnt, 3 ahead (pad-safe)
        const unsigned eon =
            (unsigned)__float_as_int(rec[(t + 1) & 3].x) & 0xFE00u;
        tv[(t + 1) & 1] = *(const f16x2*)(Tb + eon + jj4);    // lgkmcnt, 1 ahead

        const f32x4 ra = rec[t & 3];
        const f16x2 gh = tv[t & 1];
        union f16x2_f32 u23; u23.f = ra.w;
        const float y2 = (float)u23.h.x;
        const float y3 = (float)u23.h.y;

        f32x2 g = (f32x2){(float)gh.x, (float)gh.y};
        g = __builtin_elementwise_fma(w0, (f32x2){ra.y, ra.y}, g);
        g = __builtin_elementwise_fma(w1, (f32x2){ra.z, ra.z}, g);
        g = __builtin_elementwise_fma(w2, (f32x2){y2, y2}, g);
        g = __builtin_elementwise_fma(w3, (f32x2){y3, y3}, g);

        const float ez = __builtin_amdgcn_exp2f(g.x);   // exp(-2 gz)
        const float ef = __builtin_amdgcn_exp2f(g.y);   // exp(-gf)
        const float az = 1.0f + ez, af = 1.0f + ef;
        const float r = __builtin_amdgcn_rcpf(az * af); // shared rcp
        const float f = r * az;                         // sigmoid(gf)
        const float z = fmaf(2.0f, r * af, -1.0f);      // tanh(gz)

        A *= f;
        Bv = fmaf(f, Bv - z, z);   // z + f*(Bv - z)
    }

    AB[(((size_t)c * NB + b) * 2 + 0) * NH + j] = A;
    AB[(((size_t)c * NB + b) * 2 + 1) * NH + j] = Bv;

    if (c == CHUNKS - 1) {
        const f32x4 la = xa[STEPS - 1];
        union f16x2_f32 u23; u23.f = la.w;
        const size_t eo = (size_t)((unsigned)__float_as_int(la.x) & 0xFE00u);
        float go = *(const float*)((const char*)Go + (eo << 1) + (size_t)j * 4);
        go = fmaf(Wgo4[0 * NH + j], la.y, go);
        go = fmaf(Wgo4[1 * NH + j], la.z, go);
        go = fmaf(Wgo4[2 * NH + j], (float)u23.h.x, go);
        go = fmaf(Wgo4[3 * NH + j], (float)u23.h.y, go);
        Olast[b * NH + j] = __builtin_amdgcn_rcpf(1.0f + __builtin_amdgcn_exp2f(go));
    }
}

__global__ __launch_bounds__(256) void combine_kernel(
    const float* __restrict__ AB,     // [CHUNKS][B][2][256]
    const float* __restrict__ Olast,  // [B][256]
    const float* __restrict__ Wout,   // [1][256]
    const float* __restrict__ bout,   // [1]
    float* __restrict__ out)          // [B][1]
{
    const int b = blockIdx.x;
    const int j = threadIdx.x;

    float h = 0.0f;
    #pragma unroll 8
    for (int c = 0; c < CHUNKS; ++c) {
        const float A  = AB[(((size_t)c * NB + b) * 2 + 0) * NH + j];
        const float Bv = AB[(((size_t)c * NB + b) * 2 + 1) * NH + j];
        h = fmaf(A, h, Bv);
    }
    float v = Olast[b * NH + j] * h * Wout[j];

    #pragma unroll
    for (int off = 32; off > 0; off >>= 1) v += __shfl_down(v, off);
    __shared__ float red[4];
    if ((j & 63) == 0) red[j >> 6] = v;
    __syncthreads();
    if (j == 0) out[b] = red[0] + red[1] + red[2] + red[3] + bout[0];
}

extern "C" void kernel_launch(void* const* d_in, const int* in_sizes, int n_in,
                              void* d_out, int out_size, void* d_ws, size_t ws_size,
                              hipStream_t stream) {
    const float* X    = (const float*)d_in[0];
    const float* emb  = (const float*)d_in[1];
    const float* Wn   = (const float*)d_in[2];
    const float* bn   = (const float*)d_in[3];
    const float* Wc   = (const float*)d_in[4];
    const float* bc   = (const float*)d_in[5];
    const float* Wout = (const float*)d_in[6];
    const float* bout = (const float*)d_in[7];
    float* out = (float*)d_out;

    char* w = (char*)d_ws;
    f16x2* G2h  = (f16x2*)w;   w += 128 * NH * sizeof(f16x2);   // 128 KB
    float* Go   = (float*)w;   w += 128 * NH * sizeof(float);   // 128 KB
    f32x2* Wg4  = (f32x2*)w;   w += 4 * NH * sizeof(f32x2);
    float* Wgo4 = (float*)w;   w += 4 * NH * sizeof(float);
    float* AB   = (float*)w;   w += (size_t)CHUNKS * NB * 2 * NH * sizeof(float); // 4 MB
    float* Ol   = (float*)w;   w += NB * NH * sizeof(float);
    f32x4* Xp   = (f32x4*)w;   w += ((size_t)NB * NS + 4) * sizeof(f32x4);        // 2 MB + pad

    precompute_kernel<<<385, 256, 0, stream>>>(X, emb, Wn, bn, Wc, bc,
                                               G2h, Go, Wg4, Wgo4, Xp);
    dim3 gridS(256, 2);
    scan_kernel<<<gridS, 1024, 0, stream>>>(Xp, G2h, Go, Wg4, Wgo4, AB, Ol);
    combine_kernel<<<NB, 256, 0, stream>>>(AB, Ol, Wout, bout, out);
}